// Round 6
// baseline (123.798 us; speedup 1.0000x reference)
//
#include <hip/hip_runtime.h>

typedef __attribute__((ext_vector_type(8))) __bf16 bf16x8;
typedef __attribute__((ext_vector_type(4))) float f32x4;
typedef unsigned long long u64;

#define KC 256             // k-floats per LDS chunk = 1KB per row => one wave-instr per row
#define NCHUNK 8           // 2048 / 256
#define NSH 16             // atomic shards
#define OFF_D  0           // dshard[16][4096]
#define OFF_GN 65536       // gnshard[16][4096]
#define OFF_GA 131072      // gashard[16][4096]

__device__ __forceinline__ unsigned short f2bf(float x) {
    unsigned u = __float_as_uint(x);
    u += 0x7FFFu + ((u >> 16) & 1u);   // round-to-nearest-even
    return (unsigned short)(u >> 16);
}

// One block per t (200 blocks). Full K=2048 in-block: stage 128 rows x 256 k as bf16
// (whole-wave 1KB-burst loads), 3 Gram matrices via MFMA, hinge in-block,
// 16-way t-sharded atomic accumulation (no same-line storms).
__global__ __launch_bounds__(256) void cl_main(const float* __restrict__ feats,
                                               float* __restrict__ ws)
{
    const int t   = blockIdx.x;          // 0..199
    const int tid = threadIdx.x;
    const int w   = tid >> 6;            // wave 0..3
    const int l   = tid & 63;
    const int r16 = tid & 15;
    const int kg  = (tid & 63) >> 4;

    __shared__ __align__(16) unsigned short lds[128][KC];   // 64KB: rows 0-63 N, 64-127 A
    __shared__ float n2s[64], a2s[64];

    const size_t kbase = (size_t)t * 2048;

    f32x4 accD[4], accNN[4], accAA[4];
    const f32x4 zero = {0.f, 0.f, 0.f, 0.f};
    #pragma unroll
    for (int j = 0; j < 4; ++j) { accD[j] = zero; accNN[j] = zero; accAA[j] = zero; }

    const int rs = (r16 & 7) << 3;       // frag-read swizzle (frag row & 7 == r16 & 7)

    for (int c = 0; c < NCHUNK; ++c) {
        // each wave stages rows w*32 .. w*32+31; one wave-instr = 1KB contiguous
        #pragma unroll
        for (int h = 0; h < 2; ++h) {
            float4 v[16];
            #pragma unroll
            for (int rr = 0; rr < 16; ++rr) {
                const int row = w*32 + h*16 + rr;
                v[rr] = *(const float4*)(feats + (size_t)row * 409600 + kbase + c*KC + 4*l);
            }
            #pragma unroll
            for (int rr = 0; rr < 16; ++rr) {
                const int row = w*32 + h*16 + rr;
                ushort4 p;
                p.x = f2bf(v[rr].x); p.y = f2bf(v[rr].y);
                p.z = f2bf(v[rr].z); p.w = f2bf(v[rr].w);
                *(ushort4*)&lds[row][(4*l) ^ ((row & 7) << 3)] = p;
            }
        }
        __syncthreads();
        #pragma unroll
        for (int ks = 0; ks < 8; ++ks) {
            const int kb = ks*32 + kg*8;
            bf16x8 aN = *(const bf16x8*)&lds[w*16 + r16][kb ^ rs];
            bf16x8 aA = *(const bf16x8*)&lds[64 + w*16 + r16][kb ^ rs];
            #pragma unroll
            for (int jt = 0; jt < 4; ++jt) {
                bf16x8 bN = *(const bf16x8*)&lds[jt*16 + r16][kb ^ rs];
                bf16x8 bA = *(const bf16x8*)&lds[64 + jt*16 + r16][kb ^ rs];
                accD[jt]  = __builtin_amdgcn_mfma_f32_16x16x32_bf16(aN, bA, accD[jt],  0, 0, 0);
                accNN[jt] = __builtin_amdgcn_mfma_f32_16x16x32_bf16(aN, bN, accNN[jt], 0, 0, 0);
                accAA[jt] = __builtin_amdgcn_mfma_f32_16x16x32_bf16(aA, bA, accAA[jt], 0, 0, 0);
            }
        }
        __syncthreads();
    }

    // n2/a2 from Gram diagonals: diag (i,i) lives at jt==w, kg==r16>>2, r==r16&3
    if (kg == (r16 >> 2)) {
        n2s[w*16 + r16] = accNN[w][r16 & 3];
        a2s[w*16 + r16] = accAA[w][r16 & 3];
    }
    __syncthreads();

    // hinge + 16-way sharded atomic accumulation
    const int sh = (t & 15) * 4096;
    #pragma unroll
    for (int jt = 0; jt < 4; ++jt) {
        const int j = jt*16 + r16;
        const float a2v = a2s[j];
        #pragma unroll
        for (int r = 0; r < 4; ++r) {
            const int i  = w*16 + kg*4 + r;
            const int ij = i*64 + j;
            float dist2 = fmaxf(n2s[i] + a2v - 2.f * accD[jt][r], 0.f);
            float v = fmaxf(200.f - sqrtf(dist2), 0.f);
            atomicAdd(&ws[OFF_D  + sh + ij], v * v * 0.005f);   // 1/200
            atomicAdd(&ws[OFF_GN + sh + ij], accNN[jt][r]);
            atomicAdd(&ws[OFF_GA + sh + ij], accAA[jt][r]);
        }
    }
}

__global__ __launch_bounds__(1024) void cl_final(const float* __restrict__ ws,
                                                 float* __restrict__ out)
{
    const int tid = threadIdx.x;
    __shared__ u64 wmin[16];
    __shared__ int   sIdx;
    __shared__ float sDmin;

    // argmin over shard-summed dmat, first-occurrence tie-break via packed key
    u64 best = ~0ull;
    #pragma unroll
    for (int u = 0; u < 4; ++u) {
        const int ij = u*1024 + tid;
        float s = 0.f;
        #pragma unroll
        for (int sh = 0; sh < NSH; ++sh) s += ws[OFF_D + sh*4096 + ij];
        u64 key = ((u64)__float_as_uint(s) << 12) | (unsigned)ij;   // s>=0: order-preserving
        best = key < best ? key : best;
    }
    #pragma unroll
    for (int off = 32; off > 0; off >>= 1) {
        u64 o = __shfl_xor(best, off);
        best = o < best ? o : best;
    }
    if ((tid & 63) == 0) wmin[tid >> 6] = best;
    __syncthreads();
    if (tid == 0) {
        u64 m = wmin[0];
        for (int k = 1; k < 16; ++k) m = wmin[k] < m ? wmin[k] : m;
        sIdx  = (int)(m & 0xFFF);
        sDmin = __uint_as_float((unsigned)(m >> 12));
    }
    __syncthreads();
    const int idx = sIdx;
    const int mn = idx >> 6;
    const int ma = idx & 63;

    if (tid < 64) {   // wave 0
        float gcn = 0.f, gca = 0.f, rn = 0.f, ra = 0.f;
        #pragma unroll
        for (int sh = 0; sh < NSH; ++sh) {
            const int b = sh*4096;
            gcn += ws[OFF_GN + b + tid*64 + mn];
            gca += ws[OFF_GA + b + tid*64 + ma];
            rn  += ws[OFF_GN + b + tid*65];        // diag -> Rn[tid]
            ra  += ws[OFF_GA + b + tid*65];        // diag -> Ra[tid]
        }
        const float rnm = __shfl(rn, mn);
        const float ram = __shfl(ra, ma);
        float tn = (tid != mn) ? (rn + rnm - 2.f * gcn) : 0.f;
        float ta = (tid != ma) ? (ra + ram - 2.f * gca) : 0.f;
        float s = tn + ta;
        #pragma unroll
        for (int off = 32; off > 0; off >>= 1) s += __shfl_xor(s, off);
        if (tid == 0)
            out[0] = 0.001f * sDmin + s * (1.f / 12800.f);   // /(200*64)
    }
}

extern "C" void kernel_launch(void* const* d_in, const int* in_sizes, int n_in,
                              void* d_out, int out_size, void* d_ws, size_t ws_size,
                              hipStream_t stream)
{
    const float* feats = (const float*)d_in[0];
    float* out = (float*)d_out;
    float* ws  = (float*)d_ws;

    hipMemsetAsync(d_ws, 0, 3 * NSH * 4096 * sizeof(float), stream);
    cl_main<<<dim3(200), dim3(256), 0, stream>>>(feats, ws);
    cl_final<<<dim3(1), dim3(1024), 0, stream>>>(ws, out);
}